// Round 10
// baseline (388.062 us; speedup 1.0000x reference)
//
#include <hip/hip_runtime.h>
#include <stdint.h>

// Problem constants
#define IN_F   4096
#define OUT_F  4096
#define M_ROWS 8192      // 4 * 2048
#define KT     (IN_F / 64)   // 64 K-tiles of BK=64

typedef __attribute__((ext_vector_type(8))) short  bf16x8;
typedef __attribute__((ext_vector_type(4))) float  f32x4;

__device__ __forceinline__ short f2bf(float f) {
    union { float f; uint32_t u; } v; v.f = f;
    uint32_t r = v.u + 0x7FFFu + ((v.u >> 16) & 1u);
    return (short)(r >> 16);
}

__device__ __forceinline__ void load_lds16(const void* gsrc, void* lds) {
    __builtin_amdgcn_global_load_lds(
        (const __attribute__((address_space(1))) uint32_t*)gsrc,
        (__attribute__((address_space(3))) uint32_t*)lds,
        16, 0, 0);
}

// ============================================================================
// Kernel 1: FUSED prepass (verified r9): dequant + X fp32->bf16
// ============================================================================
#define DQ_BLOCKS ((OUT_F * (IN_F / 8)) / 256)      // 8192
#define XC_BLOCKS ((M_ROWS * IN_F / 8) / 256)       // 16384

__global__ void prepass_kernel(const int* __restrict__ qweight,
                               const int* __restrict__ qzeros,
                               const float* __restrict__ scales,
                               const float* __restrict__ x,
                               short* __restrict__ wt,
                               short* __restrict__ xb)
{
    const int bid = blockIdx.x;
    if (bid < DQ_BLOCKS) {
        int t  = bid * 256 + threadIdx.x;
        int n  = t >> 9;
        int kw = t & 511;
        int g  = kw >> 4;

        float s = scales[g * OUT_F + n];
        uint32_t zw = (uint32_t)qzeros[g * (OUT_F / 8) + (n >> 3)];
        float z1 = (float)((zw >> (4 * (n & 7))) & 0xFu) + 1.0f;
        uint32_t q = (uint32_t)qweight[kw * OUT_F + n];

        bf16x8 out;
#pragma unroll
        for (int i = 0; i < 8; ++i) {
            float w = s * ((float)((q >> (4 * i)) & 0xFu) - z1);
            out[i] = f2bf(w);
        }
        *reinterpret_cast<bf16x8*>(&wt[(size_t)n * IN_F + kw * 8]) = out;
    } else {
        int t = (bid - DQ_BLOCKS) * 256 + threadIdx.x;
        const float4* src = reinterpret_cast<const float4*>(x) + (size_t)t * 2;
        float4 a = src[0], b = src[1];
        bf16x8 h;
        h[0] = f2bf(a.x); h[1] = f2bf(a.y); h[2] = f2bf(a.z); h[3] = f2bf(a.w);
        h[4] = f2bf(b.x); h[5] = f2bf(b.y); h[6] = f2bf(b.z); h[7] = f2bf(b.w);
        reinterpret_cast<bf16x8*>(xb)[t] = h;
    }
}

// ============================================================================
// Kernel 2: 256x256 GEMM — A via LDS (3-slot, T2 swizzle, verified), B DIRECT
// global->VGPR single-buffered PER KS-HALF with issue-after-last-use:
//   Bc0(t+1) issued right after ks0's MFMAs (consumed t+1 ks0: ~1240cy cover)
//   Bc1(t+1) issued right after ks1's MFMAs (consumed t+1 ks1: ~1240cy cover)
// r7's failure was both halves issued at tile end (0 cover). 32 B-regs total.
// Implicit vmcnt ledger (r8-validated mechanism): in-order retire means the
// compiler's reg-dep wait on Bc0(t) (issued AFTER A(t+1) in tile t-1) retires
// A(t+1) before tile-t's end barrier publishes it. No explicit loop vmcnt.
// LDS/tile/CU: 128KB A-reads + 32KB A-writes (~1930cy) < MFMA 2484cy floor.
// T1 col-stripe: XCD owns 2 col-tiles -> 4MB B panel L2-resident (r7: ok).
// ============================================================================
#define A_SLOT 32768

__global__ __launch_bounds__(512, 2) void gemm8_kernel(
    const short* __restrict__ Xb,   // [M_ROWS][IN_F] bf16
    const short* __restrict__ WT,   // [OUT_F][IN_F] bf16
    float* __restrict__ C)          // [M_ROWS][OUT_F]
{
    __shared__ short AsBuf[3 * 256 * 64];   // 96 KB
    char* const Abase = (char*)AsBuf;

    const int tid  = threadIdx.x;
    const int lane = tid & 63;
    const int wid  = tid >> 6;     // 0..7
    const int wr   = wid >> 2;     // 0..1  (M half)
    const int wc   = wid & 3;      // 0..3  (N quarter)

    // ---- T1 col-stripe (verified r7): XCD (bid&7) owns col-tiles {2x, 2x+1}
    const int bid  = blockIdx.x;           // 0..511
    const int xcd  = bid & 7;
    const int jj   = bid >> 3;              // 0..63
    const int col0 = (xcd * 2 + (jj & 1)) * 256;
    const int row0 = (jj >> 1) * 256;

    // ---- A staging geometry (verified r2-r9): pre-swizzled source col,
    //      linear LDS dest (rule 21)
    const int rL0 = tid >> 3;
    const int csw = ((tid & 7) << 3) ^ ((rL0 & 7) << 3);
    const short* gA[4]; int dOff[4];
#pragma unroll
    for (int L = 0; L < 4; ++L) {
        gA[L] = Xb + (size_t)(row0 + L * 64 + rL0) * IN_F + csw;
        dOff[L] = L * 8192 + tid * 16;
    }

    // ---- A read geometry (verified): frag(ks) at byte k0 ^ (ks<<6)
    const int frow = lane & 15;
    const int k0   = ((lane >> 4) << 4) ^ ((frow & 7) << 4);

    // ---- B direct-load geometry (mapping validated r5-r7):
    //      lane reads WT[col0 + wc*64 + n*16 + (lane&15)][t*64 + (lane>>4)*8 + 32*ks]
    const short* gBf = WT + (size_t)(col0 + wc * 64 + frow) * IN_F + ((lane >> 4) << 3);

    f32x4 acc[8][4] = {};
    bf16x8 Bc0[4], Bc1[4];   // per-ks named sets, literal indices only

    // ---- prologue: A(0)->s0, A(1)->s1 (glds), then B(0) halves (reg loads
    //      AFTER A(1): B-retire => A-retire invariant for the implicit ledger)
#pragma unroll
    for (int L = 0; L < 4; ++L) load_lds16(gA[L],      Abase + 0 * A_SLOT + dOff[L]);
#pragma unroll
    for (int L = 0; L < 4; ++L) load_lds16(gA[L] + 64, Abase + 1 * A_SLOT + dOff[L]);
#pragma unroll
    for (int n = 0; n < 4; ++n) {
        const short* p = gBf + (size_t)n * 16 * IN_F;
        Bc0[n] = *reinterpret_cast<const bf16x8*>(p);
        Bc1[n] = *reinterpret_cast<const bf16x8*>(p + 32);
    }
    asm volatile("s_waitcnt vmcnt(12)" ::: "memory");   // drain A(0) only
    __builtin_amdgcn_s_barrier();

    int sA  = 0;   // t % 3
    int sA2 = 2;   // (t+2) % 3

    for (int t = 0; t < KT; ++t) {
        char* Ab = Abase + sA * A_SLOT;
        const bool pf = (t + 1 < KT);

        // -- stage A(t+2) -> LDS slot (t+2)%3 (WAR safe: slot last read in
        //    tile t-1, whose readers passed the end-of-(t-1) barrier)
        if (t + 2 < KT) {
            char* An = Abase + sA2 * A_SLOT;
#pragma unroll
            for (int L = 0; L < 4; ++L)
                load_lds16(gA[L] + (size_t)(t + 2) * 64, An + dOff[L]);
        }

        // ============ ks = 0 : consumes Bc0(t) ============
        {
            const int kb = k0;
            {
                bf16x8 af[4];
#pragma unroll
                for (int m = 0; m < 4; ++m) {
                    const int r = wr * 128 + m * 16 + frow;
                    af[m] = *reinterpret_cast<const bf16x8*>(Ab + r * 128 + kb);
                }
                __builtin_amdgcn_s_setprio(1);
#pragma unroll
                for (int m = 0; m < 4; ++m) {
                    acc[m][0] = __builtin_amdgcn_mfma_f32_16x16x32_bf16(af[m], Bc0[0], acc[m][0], 0, 0, 0);
                    acc[m][1] = __builtin_amdgcn_mfma_f32_16x16x32_bf16(af[m], Bc0[1], acc[m][1], 0, 0, 0);
                    acc[m][2] = __builtin_amdgcn_mfma_f32_16x16x32_bf16(af[m], Bc0[2], acc[m][2], 0, 0, 0);
                    acc[m][3] = __builtin_amdgcn_mfma_f32_16x16x32_bf16(af[m], Bc0[3], acc[m][3], 0, 0, 0);
                }
                __builtin_amdgcn_s_setprio(0);
            }
            {
                bf16x8 ag[4];
#pragma unroll
                for (int m = 0; m < 4; ++m) {
                    const int r = wr * 128 + (m + 4) * 16 + frow;
                    ag[m] = *reinterpret_cast<const bf16x8*>(Ab + r * 128 + kb);
                }
                __builtin_amdgcn_s_setprio(1);
#pragma unroll
                for (int m = 0; m < 4; ++m) {
                    acc[m + 4][0] = __builtin_amdgcn_mfma_f32_16x16x32_bf16(ag[m], Bc0[0], acc[m + 4][0], 0, 0, 0);
                    acc[m + 4][1] = __builtin_amdgcn_mfma_f32_16x16x32_bf16(ag[m], Bc0[1], acc[m + 4][1], 0, 0, 0);
                    acc[m + 4][2] = __builtin_amdgcn_mfma_f32_16x16x32_bf16(ag[m], Bc0[2], acc[m + 4][2], 0, 0, 0);
                    acc[m + 4][3] = __builtin_amdgcn_mfma_f32_16x16x32_bf16(ag[m], Bc0[3], acc[m + 4][3], 0, 0, 0);
                }
                __builtin_amdgcn_s_setprio(0);
            }
        }

        // -- issue Bc0(t+1) NOW (last use of Bc0(t) just retired; consumption
        //    is t+1 ks0 => one ks-block (~1240cy) + barrier of latency cover)
        if (pf) {
#pragma unroll
            for (int n = 0; n < 4; ++n) {
                const short* p = gBf + (size_t)n * 16 * IN_F + (size_t)(t + 1) * 64;
                Bc0[n] = *reinterpret_cast<const bf16x8*>(p);
            }
        }

        // ============ ks = 1 : consumes Bc1(t) ============
        {
            const int kb = k0 ^ 64;
            {
                bf16x8 af[4];
#pragma unroll
                for (int m = 0; m < 4; ++m) {
                    const int r = wr * 128 + m * 16 + frow;
                    af[m] = *reinterpret_cast<const bf16x8*>(Ab + r * 128 + kb);
                }
                __builtin_amdgcn_s_setprio(1);
#pragma unroll
                for (int m = 0; m < 4; ++m) {
                    acc[m][0] = __builtin_amdgcn_mfma_f32_16x16x32_bf16(af[m], Bc1[0], acc[m][0], 0, 0, 0);
                    acc[m][1] = __builtin_amdgcn_mfma_f32_16x16x32_bf16(af[m], Bc1[1], acc[m][1], 0, 0, 0);
                    acc[m][2] = __builtin_amdgcn_mfma_f32_16x16x32_bf16(af[m], Bc1[2], acc[m][2], 0, 0, 0);
                    acc[m][3] = __builtin_amdgcn_mfma_f32_16x16x32_bf16(af[m], Bc1[3], acc[m][3], 0, 0, 0);
                }
                __builtin_amdgcn_s_setprio(0);
            }
            {
                bf16x8 ag[4];
#pragma unroll
                for (int m = 0; m < 4; ++m) {
                    const int r = wr * 128 + (m + 4) * 16 + frow;
                    ag[m] = *reinterpret_cast<const bf16x8*>(Ab + r * 128 + kb);
                }
                __builtin_amdgcn_s_setprio(1);
#pragma unroll
                for (int m = 0; m < 4; ++m) {
                    acc[m + 4][0] = __builtin_amdgcn_mfma_f32_16x16x32_bf16(ag[m], Bc1[0], acc[m + 4][0], 0, 0, 0);
                    acc[m + 4][1] = __builtin_amdgcn_mfma_f32_16x16x32_bf16(ag[m], Bc1[1], acc[m + 4][1], 0, 0, 0);
                    acc[m + 4][2] = __builtin_amdgcn_mfma_f32_16x16x32_bf16(ag[m], Bc1[2], acc[m + 4][2], 0, 0, 0);
                    acc[m + 4][3] = __builtin_amdgcn_mfma_f32_16x16x32_bf16(ag[m], Bc1[3], acc[m + 4][3], 0, 0, 0);
                }
                __builtin_amdgcn_s_setprio(0);
            }
        }

        // -- issue Bc1(t+1) (cover: barrier + t+1's ks0 block)
        if (pf) {
#pragma unroll
            for (int n = 0; n < 4; ++n) {
                const short* p = gBf + (size_t)n * 16 * IN_F + (size_t)(t + 1) * 64;
                Bc1[n] = *reinterpret_cast<const bf16x8*>(p + 32);
            }
        }

        __builtin_amdgcn_s_barrier();   // no vm drain: loads span the barrier

        sA  = (sA  < 2) ? sA  + 1 : 0;
        sA2 = (sA2 < 2) ? sA2 + 1 : 0;
    }

    // ---- epilogue: C/D layout col=lane&15, row=(lane>>4)*4+reg (verified)
    const int crow = (lane >> 4) * 4;
    const int ccol = lane & 15;
#pragma unroll
    for (int fm = 0; fm < 8; ++fm)
#pragma unroll
        for (int fn = 0; fn < 4; ++fn)
#pragma unroll
            for (int r = 0; r < 4; ++r) {
                const int row = row0 + wr * 128 + fm * 16 + crow + r;
                const int col = col0 + wc * 64 + fn * 16 + ccol;
                C[(size_t)row * OUT_F + col] = acc[fm][fn][r];
            }
}

// ============================================================================
// Fallback GEMM (round-1, verified): used only if ws too small for Xb
// ============================================================================
#define BM 128
#define BN 128
#define BK 64

__global__ __launch_bounds__(256, 2) void gemm_x_wt_kernel(
    const float* __restrict__ X,
    const short* __restrict__ WT,
    float* __restrict__ C)
{
    __shared__ short As2[BM * BK];
    __shared__ short Bs2[BN * BK];

    const int bn = blockIdx.x;
    const int bm = blockIdx.y;
    const int tid  = threadIdx.x;
    const int lane = tid & 63;
    const int wid  = tid >> 6;
    const int wr   = wid >> 1;
    const int wc   = wid & 1;

    const int row0 = bm * BM;
    const int col0 = bn * BN;
    const int frow = lane & 15;
    const int fk   = (lane >> 4) * 8;

    f32x4 acc[4][4] = {};

    for (int kt = 0; kt < IN_F / BK; ++kt) {
        float4 a0[4], a1[4];
#pragma unroll
        for (int j = 0; j < 4; ++j) {
            const int flat = (j * 256 + tid) * 8;
            const int r = flat >> 6;
            const int c = flat & (BK - 1);
            const float* src = X + (size_t)(row0 + r) * IN_F + kt * BK + c;
            a0[j] = *reinterpret_cast<const float4*>(src);
            a1[j] = *reinterpret_cast<const float4*>(src + 4);
        }
        __syncthreads();
#pragma unroll
        for (int j = 0; j < 4; ++j) {
            const int flat = (j * 256 + tid) * 8;
            const int r = flat >> 6;
            const int c = flat & (BK - 1);
            load_lds16(WT + (size_t)(col0 + r) * IN_F + kt * BK + c, &Bs2[flat]);
        }
#pragma unroll
        for (int j = 0; j < 4; ++j) {
            const int flat = (j * 256 + tid) * 8;
            bf16x8 h;
            h[0] = f2bf(a0[j].x); h[1] = f2bf(a0[j].y);
            h[2] = f2bf(a0[j].z); h[3] = f2bf(a0[j].w);
            h[4] = f2bf(a1[j].x); h[5] = f2bf(a1[j].y);
            h[6] = f2bf(a1[j].z); h[7] = f2bf(a1[j].w);
            *reinterpret_cast<bf16x8*>(&As2[flat]) = h;
        }
        __syncthreads();
#pragma unroll
        for (int s = 0; s < 2; ++s) {
            bf16x8 af[4], bfr[4];
#pragma unroll
            for (int m = 0; m < 4; ++m) {
                const int row = wr * 64 + m * 16 + frow;
                af[m] = *reinterpret_cast<const bf16x8*>(&As2[row * BK + s * 32 + fk]);
            }
#pragma unroll
            for (int n = 0; n < 4; ++n) {
                const int col = wc * 64 + n * 16 + frow;
                bfr[n] = *reinterpret_cast<const bf16x8*>(&Bs2[col * BK + s * 32 + fk]);
            }
#pragma unroll
            for (int m = 0; m < 4; ++m)
#pragma unroll
                for (int n = 0; n < 4; ++n)
                    acc[m][n] = __builtin_amdgcn_mfma_f32_16x16x32_bf16(
                        af[m], bfr[n], acc[m][n], 0, 0, 0);
        }
    }

    const int crow = (lane >> 4) * 4;
    const int ccol = lane & 15;
#pragma unroll
    for (int m = 0; m < 4; ++m)
#pragma unroll
        for (int n = 0; n < 4; ++n)
#pragma unroll
            for (int r = 0; r < 4; ++r) {
                const int row = row0 + wr * 64 + m * 16 + crow + r;
                const int col = col0 + wc * 64 + n * 16 + ccol;
                C[(size_t)row * OUT_F + col] = acc[m][n][r];
            }
}

// ============================================================================
extern "C" void kernel_launch(void* const* d_in, const int* in_sizes, int n_in,
                              void* d_out, int out_size, void* d_ws, size_t ws_size,
                              hipStream_t stream) {
    const float* x       = (const float*)d_in[0];
    const int*   qweight = (const int*)  d_in[1];
    const int*   qzeros  = (const int*)  d_in[2];
    const float* scales  = (const float*)d_in[3];
    float*       out     = (float*)d_out;

    const size_t WT_BYTES = (size_t)OUT_F * IN_F * 2;   // 33.5 MB
    const size_t XB_BYTES = (size_t)M_ROWS * IN_F * 2;  // 67.1 MB

    short* wt = (short*)d_ws;

    if (ws_size >= WT_BYTES + XB_BYTES) {
        short* xb = (short*)((char*)d_ws + WT_BYTES);
        prepass_kernel<<<DQ_BLOCKS + XC_BLOCKS, 256, 0, stream>>>(
            qweight, qzeros, scales, x, wt, xb);
        gemm8_kernel<<<(M_ROWS / 256) * (OUT_F / 256), 512, 0, stream>>>(xb, wt, out);
    } else {
        prepass_kernel<<<DQ_BLOCKS, 256, 0, stream>>>(
            qweight, qzeros, scales, x, wt, (short*)nullptr);
        dim3 grid(OUT_F / BN, M_ROWS / BM);
        gemm_x_wt_kernel<<<grid, 256, 0, stream>>>(x, wt, out);
    }
}

// Round 11
// 282.582 us; speedup vs baseline: 1.3733x; 1.3733x over previous
//
#include <hip/hip_runtime.h>
#include <stdint.h>

// Problem constants
#define IN_F   4096
#define OUT_F  4096
#define M_ROWS 8192      // 4 * 2048
#define KT     (IN_F / 64)   // 64 K-tiles of BK=64

typedef __attribute__((ext_vector_type(8))) short  bf16x8;
typedef __attribute__((ext_vector_type(4))) float  f32x4;

__device__ __forceinline__ short f2bf(float f) {
    union { float f; uint32_t u; } v; v.f = f;
    uint32_t r = v.u + 0x7FFFu + ((v.u >> 16) & 1u);
    return (short)(r >> 16);
}

__device__ __forceinline__ void load_lds16(const void* gsrc, void* lds) {
    __builtin_amdgcn_global_load_lds(
        (const __attribute__((address_space(1))) uint32_t*)gsrc,
        (__attribute__((address_space(3))) uint32_t*)lds,
        16, 0, 0);
}

// ============================================================================
// Kernel 1: FUSED prepass (verified r9): dequant + X fp32->bf16
// ============================================================================
#define DQ_BLOCKS ((OUT_F * (IN_F / 8)) / 256)      // 8192
#define XC_BLOCKS ((M_ROWS * IN_F / 8) / 256)       // 16384

__global__ void prepass_kernel(const int* __restrict__ qweight,
                               const int* __restrict__ qzeros,
                               const float* __restrict__ scales,
                               const float* __restrict__ x,
                               short* __restrict__ wt,
                               short* __restrict__ xb)
{
    const int bid = blockIdx.x;
    if (bid < DQ_BLOCKS) {
        int t  = bid * 256 + threadIdx.x;
        int n  = t >> 9;
        int kw = t & 511;
        int g  = kw >> 4;

        float s = scales[g * OUT_F + n];
        uint32_t zw = (uint32_t)qzeros[g * (OUT_F / 8) + (n >> 3)];
        float z1 = (float)((zw >> (4 * (n & 7))) & 0xFu) + 1.0f;
        uint32_t q = (uint32_t)qweight[kw * OUT_F + n];

        bf16x8 out;
#pragma unroll
        for (int i = 0; i < 8; ++i) {
            float w = s * ((float)((q >> (4 * i)) & 0xFu) - z1);
            out[i] = f2bf(w);
        }
        *reinterpret_cast<bf16x8*>(&wt[(size_t)n * IN_F + kw * 8]) = out;
    } else {
        int t = (bid - DQ_BLOCKS) * 256 + threadIdx.x;
        const float4* src = reinterpret_cast<const float4*>(x) + (size_t)t * 2;
        float4 a = src[0], b = src[1];
        bf16x8 h;
        h[0] = f2bf(a.x); h[1] = f2bf(a.y); h[2] = f2bf(a.z); h[3] = f2bf(a.w);
        h[4] = f2bf(b.x); h[5] = f2bf(b.y); h[6] = f2bf(b.z); h[7] = f2bf(b.w);
        reinterpret_cast<bf16x8*>(xb)[t] = h;
    }
}

// ============================================================================
// Kernel 2: 256x256 GEMM — r4 slots/ledger/swizzle + m201-style 4-phase split.
//   Per K-tile, 4 phases (ks-half x m-half), each:
//     {dedup ds_reads (8 or 4) ; 2 staging gloads} -> s_barrier ->
//     lgkmcnt(0) -> setprio(1) -> 16 MFMA -> setprio(0) -> s_barrier
//   Dedup: bfr[ks] read once (P0/P2), af halves once each. 24 reads/tile/wave.
//   Staging: B(t+1) split P0/P1, A(t+2) split P2/P3 (2 gloads each phase).
//   Counted vmcnt(4) at tile end only (r4 ledger: drains A(t+1)+B(t+1),
//   keeps A(t+2)'s 4 in flight; never 0 mid-loop). NO sched_barrier (m141).
//   Differences vs failed r3: counted (not drain-0) vmcnt, dedup'd (not 2x)
//   reads, staging spread (not clumped), no sched_barrier order-pinning.
// ============================================================================
#define A_SLOT 32768
#define B_SLOT 32768

__global__ __launch_bounds__(512, 1) void gemm8_kernel(
    const short* __restrict__ Xb,   // [M_ROWS][IN_F] bf16
    const short* __restrict__ WT,   // [OUT_F][IN_F] bf16
    float* __restrict__ C)          // [M_ROWS][OUT_F]
{
    __shared__ short AsBuf[3 * 256 * 64];   // 96 KB
    __shared__ short BsBuf[2 * 256 * 64];   // 64 KB
    char* const Abase = (char*)AsBuf;
    char* const Bbase = (char*)BsBuf;

    const int tid  = threadIdx.x;
    const int lane = tid & 63;
    const int wid  = tid >> 6;     // 0..7
    const int wr   = wid >> 2;     // 0..1  (M half)
    const int wc   = wid & 3;      // 0..3  (N quarter)

    const int row0 = blockIdx.y * 256;
    const int col0 = blockIdx.x * 256;

    // ---- staging geometry (verified r2-r10): pre-swizzled source col
    //      (rule 21), linear LDS dest; load L covers slot bytes [L*8192+tid*16)
    const int rL0 = tid >> 3;
    const int csw = ((tid & 7) << 3) ^ ((rL0 & 7) << 3);
    const short* gA[4]; const short* gB[4]; int dOff[4];
#pragma unroll
    for (int L = 0; L < 4; ++L) {
        const int r = L * 64 + rL0;
        gA[L] = Xb + (size_t)(row0 + r) * IN_F + csw;
        gB[L] = WT + (size_t)(col0 + r) * IN_F + csw;
        dOff[L] = L * 8192 + tid * 16;
    }

    // ---- read geometry (verified): frag(ks) at byte k0 ^ (ks<<6)
    const int frow = lane & 15;
    const int k0   = ((lane >> 4) << 4) ^ ((frow & 7) << 4);

    f32x4 acc[8][4] = {};

    // ---- prologue (r4 ledger): A(0), B(0), A(1); vmcnt(4) leaves A(1) flying
#pragma unroll
    for (int L = 0; L < 4; ++L) load_lds16(gA[L],      Abase + 0 * A_SLOT + dOff[L]);
#pragma unroll
    for (int L = 0; L < 4; ++L) load_lds16(gB[L],      Bbase + 0 * B_SLOT + dOff[L]);
#pragma unroll
    for (int L = 0; L < 4; ++L) load_lds16(gA[L] + 64, Abase + 1 * A_SLOT + dOff[L]);
    asm volatile("s_waitcnt vmcnt(4)" ::: "memory");
    __builtin_amdgcn_s_barrier();

    int sA = 0;   // A slot of tile t   (t % 3)
    int sB = 0;   // B slot of tile t   (t & 1)

    for (int t = 0; t < KT; ++t) {
        char* Ab = Abase + sA * A_SLOT;
        char* Bb = Bbase + sB * B_SLOT;
        const int sA2 = (sA >= 1) ? sA - 1 : 2;       // (t+2) % 3
        char* An = Abase + sA2 * A_SLOT;
        char* Bn = Bbase + (sB ^ 1) * B_SLOT;
        const bool pfB = (t + 1 < KT);
        const bool pfA = (t + 2 < KT);

        bf16x8 bfr[4];   // B frags of current ks; live across the 2 m-phases

#pragma unroll
        for (int ks = 0; ks < 2; ++ks) {
            const int kb = k0 ^ (ks << 6);

            // ======== phase (ks, m-half 0) ========
            {
                bf16x8 af[4];
#pragma unroll
                for (int m = 0; m < 4; ++m) {
                    const int r = wr * 128 + m * 16 + frow;
                    af[m] = *reinterpret_cast<const bf16x8*>(Ab + r * 128 + kb);
                }
#pragma unroll
                for (int n = 0; n < 4; ++n) {
                    const int r = wc * 64 + n * 16 + frow;
                    bfr[n] = *reinterpret_cast<const bf16x8*>(Bb + r * 128 + kb);
                }
                // staging: ks0 -> B(t+1) piece 0; ks1 -> A(t+2) piece 0
                if (ks == 0) {
                    if (pfB) {
                        load_lds16(gB[0] + (size_t)(t + 1) * 64, Bn + dOff[0]);
                        load_lds16(gB[1] + (size_t)(t + 1) * 64, Bn + dOff[1]);
                    }
                } else {
                    if (pfA) {
                        load_lds16(gA[0] + (size_t)(t + 2) * 64, An + dOff[0]);
                        load_lds16(gA[1] + (size_t)(t + 2) * 64, An + dOff[1]);
                    }
                }

                __builtin_amdgcn_s_barrier();
                asm volatile("s_waitcnt lgkmcnt(0)" ::: "memory");
                __builtin_amdgcn_s_setprio(1);
#pragma unroll
                for (int m = 0; m < 4; ++m)
#pragma unroll
                    for (int n = 0; n < 4; ++n)
                        acc[m][n] = __builtin_amdgcn_mfma_f32_16x16x32_bf16(
                            af[m], bfr[n], acc[m][n], 0, 0, 0);
                __builtin_amdgcn_s_setprio(0);
                __builtin_amdgcn_s_barrier();
            }

            // ======== phase (ks, m-half 1) ========
            {
                bf16x8 ag[4];
#pragma unroll
                for (int m = 0; m < 4; ++m) {
                    const int r = wr * 128 + (m + 4) * 16 + frow;
                    ag[m] = *reinterpret_cast<const bf16x8*>(Ab + r * 128 + kb);
                }
                // staging: ks0 -> B(t+1) piece 1; ks1 -> A(t+2) piece 1
                if (ks == 0) {
                    if (pfB) {
                        load_lds16(gB[2] + (size_t)(t + 1) * 64, Bn + dOff[2]);
                        load_lds16(gB[3] + (size_t)(t + 1) * 64, Bn + dOff[3]);
                    }
                } else {
                    if (pfA) {
                        load_lds16(gA[2] + (size_t)(t + 2) * 64, An + dOff[2]);
                        load_lds16(gA[3] + (size_t)(t + 2) * 64, An + dOff[3]);
                    }
                }

                __builtin_amdgcn_s_barrier();
                asm volatile("s_waitcnt lgkmcnt(0)" ::: "memory");
                __builtin_amdgcn_s_setprio(1);
#pragma unroll
                for (int m = 0; m < 4; ++m)
#pragma unroll
                    for (int n = 0; n < 4; ++n)
                        acc[m + 4][n] = __builtin_amdgcn_mfma_f32_16x16x32_bf16(
                            ag[m], bfr[n], acc[m + 4][n], 0, 0, 0);
                __builtin_amdgcn_s_setprio(0);

                // end-of-tile counted wait before the trailing barrier
                if (ks == 1) {
                    if (t < KT - 2)
                        asm volatile("s_waitcnt vmcnt(4)" ::: "memory");
                    else if (t == KT - 2)
                        asm volatile("s_waitcnt vmcnt(0)" ::: "memory");
                }
                __builtin_amdgcn_s_barrier();
            }
        }

        sA = (sA < 2) ? sA + 1 : 0;
        sB ^= 1;
    }

    // ---- epilogue: C/D layout col=lane&15, row=(lane>>4)*4+reg (verified)
    const int crow = (lane >> 4) * 4;
    const int ccol = lane & 15;
#pragma unroll
    for (int fm = 0; fm < 8; ++fm)
#pragma unroll
        for (int fn = 0; fn < 4; ++fn)
#pragma unroll
            for (int r = 0; r < 4; ++r) {
                const int row = row0 + wr * 128 + fm * 16 + crow + r;
                const int col = col0 + wc * 64 + fn * 16 + ccol;
                C[(size_t)row * OUT_F + col] = acc[fm][fn][r];
            }
}

// ============================================================================
// Fallback GEMM (round-1, verified): used only if ws too small for Xb
// ============================================================================
#define BM 128
#define BN 128
#define BK 64

__global__ __launch_bounds__(256, 2) void gemm_x_wt_kernel(
    const float* __restrict__ X,
    const short* __restrict__ WT,
    float* __restrict__ C)
{
    __shared__ short As2[BM * BK];
    __shared__ short Bs2[BN * BK];

    const int bn = blockIdx.x;
    const int bm = blockIdx.y;
    const int tid  = threadIdx.x;
    const int lane = tid & 63;
    const int wid  = tid >> 6;
    const int wr   = wid >> 1;
    const int wc   = wid & 1;

    const int row0 = bm * BM;
    const int col0 = bn * BN;
    const int frow = lane & 15;
    const int fk   = (lane >> 4) * 8;

    f32x4 acc[4][4] = {};

    for (int kt = 0; kt < IN_F / BK; ++kt) {
        float4 a0[4], a1[4];
#pragma unroll
        for (int j = 0; j < 4; ++j) {
            const int flat = (j * 256 + tid) * 8;
            const int r = flat >> 6;
            const int c = flat & (BK - 1);
            const float* src = X + (size_t)(row0 + r) * IN_F + kt * BK + c;
            a0[j] = *reinterpret_cast<const float4*>(src);
            a1[j] = *reinterpret_cast<const float4*>(src + 4);
        }
        __syncthreads();
#pragma unroll
        for (int j = 0; j < 4; ++j) {
            const int flat = (j * 256 + tid) * 8;
            const int r = flat >> 6;
            const int c = flat & (BK - 1);
            load_lds16(WT + (size_t)(col0 + r) * IN_F + kt * BK + c, &Bs2[flat]);
        }
#pragma unroll
        for (int j = 0; j < 4; ++j) {
            const int flat = (j * 256 + tid) * 8;
            bf16x8 h;
            h[0] = f2bf(a0[j].x); h[1] = f2bf(a0[j].y);
            h[2] = f2bf(a0[j].z); h[3] = f2bf(a0[j].w);
            h[4] = f2bf(a1[j].x); h[5] = f2bf(a1[j].y);
            h[6] = f2bf(a1[j].z); h[7] = f2bf(a1[j].w);
            *reinterpret_cast<bf16x8*>(&As2[flat]) = h;
        }
        __syncthreads();
#pragma unroll
        for (int s = 0; s < 2; ++s) {
            bf16x8 af[4], bfr[4];
#pragma unroll
            for (int m = 0; m < 4; ++m) {
                const int row = wr * 64 + m * 16 + frow;
                af[m] = *reinterpret_cast<const bf16x8*>(&As2[row * BK + s * 32 + fk]);
            }
#pragma unroll
            for (int n = 0; n < 4; ++n) {
                const int col = wc * 64 + n * 16 + frow;
                bfr[n] = *reinterpret_cast<const bf16x8*>(&Bs2[col * BK + s * 32 + fk]);
            }
#pragma unroll
            for (int m = 0; m < 4; ++m)
#pragma unroll
                for (int n = 0; n < 4; ++n)
                    acc[m][n] = __builtin_amdgcn_mfma_f32_16x16x32_bf16(
                        af[m], bfr[n], acc[m][n], 0, 0, 0);
        }
    }

    const int crow = (lane >> 4) * 4;
    const int ccol = lane & 15;
#pragma unroll
    for (int m = 0; m < 4; ++m)
#pragma unroll
        for (int n = 0; n < 4; ++n)
#pragma unroll
            for (int r = 0; r < 4; ++r) {
                const int row = row0 + wr * 64 + m * 16 + crow + r;
                const int col = col0 + wc * 64 + n * 16 + ccol;
                C[(size_t)row * OUT_F + col] = acc[m][n][r];
            }
}

// ============================================================================
extern "C" void kernel_launch(void* const* d_in, const int* in_sizes, int n_in,
                              void* d_out, int out_size, void* d_ws, size_t ws_size,
                              hipStream_t stream) {
    const float* x       = (const float*)d_in[0];
    const int*   qweight = (const int*)  d_in[1];
    const int*   qzeros  = (const int*)  d_in[2];
    const float* scales  = (const float*)d_in[3];
    float*       out     = (float*)d_out;

    const size_t WT_BYTES = (size_t)OUT_F * IN_F * 2;   // 33.5 MB
    const size_t XB_BYTES = (size_t)M_ROWS * IN_F * 2;  // 67.1 MB

    short* wt = (short*)d_ws;

    if (ws_size >= WT_BYTES + XB_BYTES) {
        short* xb = (short*)((char*)d_ws + WT_BYTES);
        prepass_kernel<<<DQ_BLOCKS + XC_BLOCKS, 256, 0, stream>>>(
            qweight, qzeros, scales, x, wt, xb);
        dim3 grid(OUT_F / 256, M_ROWS / 256);   // (16, 32)
        gemm8_kernel<<<grid, 512, 0, stream>>>(xb, wt, out);
    } else {
        prepass_kernel<<<DQ_BLOCKS, 256, 0, stream>>>(
            qweight, qzeros, scales, x, wt, (short*)nullptr);
        dim3 grid(OUT_F / BN, M_ROWS / BM);
        gemm_x_wt_kernel<<<grid, 256, 0, stream>>>(x, wt, out);
    }
}

// Round 12
// 268.739 us; speedup vs baseline: 1.4440x; 1.0515x over previous
//
#include <hip/hip_runtime.h>
#include <stdint.h>

// Problem constants
#define IN_F   4096
#define OUT_F  4096
#define M_ROWS 8192      // 4 * 2048
#define KT     (IN_F / 64)   // 64 K-tiles of BK=64

typedef __attribute__((ext_vector_type(8))) short  bf16x8;
typedef __attribute__((ext_vector_type(4))) float  f32x4;

__device__ __forceinline__ short f2bf(float f) {
    union { float f; uint32_t u; } v; v.f = f;
    uint32_t r = v.u + 0x7FFFu + ((v.u >> 16) & 1u);
    return (short)(r >> 16);
}

__device__ __forceinline__ void load_lds16(const void* gsrc, void* lds) {
    __builtin_amdgcn_global_load_lds(
        (const __attribute__((address_space(1))) uint32_t*)gsrc,
        (__attribute__((address_space(3))) uint32_t*)lds,
        16, 0, 0);
}

// ============================================================================
// Kernel 1: FUSED prepass (verified r9): dequant + X fp32->bf16
// ============================================================================
#define DQ_BLOCKS ((OUT_F * (IN_F / 8)) / 256)      // 8192
#define XC_BLOCKS ((M_ROWS * IN_F / 8) / 256)       // 16384

__global__ void prepass_kernel(const int* __restrict__ qweight,
                               const int* __restrict__ qzeros,
                               const float* __restrict__ scales,
                               const float* __restrict__ x,
                               short* __restrict__ wt,
                               short* __restrict__ xb)
{
    const int bid = blockIdx.x;
    if (bid < DQ_BLOCKS) {
        int t  = bid * 256 + threadIdx.x;
        int n  = t >> 9;
        int kw = t & 511;
        int g  = kw >> 4;

        float s = scales[g * OUT_F + n];
        uint32_t zw = (uint32_t)qzeros[g * (OUT_F / 8) + (n >> 3)];
        float z1 = (float)((zw >> (4 * (n & 7))) & 0xFu) + 1.0f;
        uint32_t q = (uint32_t)qweight[kw * OUT_F + n];

        bf16x8 out;
#pragma unroll
        for (int i = 0; i < 8; ++i) {
            float w = s * ((float)((q >> (4 * i)) & 0xFu) - z1);
            out[i] = f2bf(w);
        }
        *reinterpret_cast<bf16x8*>(&wt[(size_t)n * IN_F + kw * 8]) = out;
    } else {
        int t = (bid - DQ_BLOCKS) * 256 + threadIdx.x;
        const float4* src = reinterpret_cast<const float4*>(x) + (size_t)t * 2;
        float4 a = src[0], b = src[1];
        bf16x8 h;
        h[0] = f2bf(a.x); h[1] = f2bf(a.y); h[2] = f2bf(a.z); h[3] = f2bf(a.w);
        h[4] = f2bf(b.x); h[5] = f2bf(b.y); h[6] = f2bf(b.z); h[7] = f2bf(b.w);
        reinterpret_cast<bf16x8*>(xb)[t] = h;
    }
}

// ============================================================================
// Kernel 2: 256x256 GEMM — r4 slots/ledger/swizzle/1-barrier loop, but
//   16 WAVES (1024 thr, 4Mx4N), per-wave 64x64 output:
//   acc 64 AGPR + ~56 VGPR -> fits 128-reg budget at 4 WAVES/SIMD (2x r4's
//   occupancy). r11 analysis: r4 is latency-bound (per-SIMD MFMA busy ~14%,
//   LDS port ~60%, wall 4444cy >> both) — TLP is the untried lever.
//   Cost: read amplification 192->256KB/tile (smaller wave tiles); port
//   ~2560cy @128B/cy ~= MFMA floor 2484cy, both << 4444.
//   Ledger: per tile stage B(t+1)[2 glds] then A(t+2)[2 glds]; end-of-tile
//   vmcnt(2) drains A(t+1)+B(t+1), keeps A(t+2). t==KT-2: vmcnt(0).
// ============================================================================
#define A_SLOT 32768
#define B_SLOT 32768

__global__ __launch_bounds__(1024, 1) void gemm16_kernel(
    const short* __restrict__ Xb,   // [M_ROWS][IN_F] bf16
    const short* __restrict__ WT,   // [OUT_F][IN_F] bf16
    float* __restrict__ C)          // [M_ROWS][OUT_F]
{
    __shared__ short AsBuf[3 * 256 * 64];   // 96 KB
    __shared__ short BsBuf[2 * 256 * 64];   // 64 KB
    char* const Abase = (char*)AsBuf;
    char* const Bbase = (char*)BsBuf;

    const int tid  = threadIdx.x;   // 0..1023
    const int lane = tid & 63;
    const int wid  = tid >> 6;      // 0..15
    const int wr   = wid >> 2;      // 0..3  (M quarter)
    const int wc   = wid & 3;       // 0..3  (N quarter)

    const int row0 = blockIdx.y * 256;
    const int col0 = blockIdx.x * 256;

    // ---- staging geometry: 1024 threads cover a 32KB slot in 2 glds each.
    //      Thread covers slot bytes [L*16384 + tid*16); row = L*128 + (tid>>3).
    //      Pre-swizzled source col (rule 21, verified r2-r11): row&7 == rL0&7.
    const int rL0 = tid >> 3;                               // 0..127
    const int csw = ((tid & 7) << 3) ^ ((rL0 & 7) << 3);
    const short* gA[2]; const short* gB[2]; int dOff[2];
#pragma unroll
    for (int L = 0; L < 2; ++L) {
        const int r = L * 128 + rL0;
        gA[L] = Xb + (size_t)(row0 + r) * IN_F + csw;
        gB[L] = WT + (size_t)(col0 + r) * IN_F + csw;
        dOff[L] = L * 16384 + tid * 16;
    }

    // ---- read geometry (verified): frag(ks) at byte k0 ^ (ks<<6)
    const int frow = lane & 15;
    const int k0   = ((lane >> 4) << 4) ^ ((frow & 7) << 4);

    f32x4 acc[4][4] = {};   // 64 AGPR: wave's 64x64 output

    // ---- prologue: A(0)[2], B(0)[2], A(1)[2]; vmcnt(2) leaves A(1) flying
#pragma unroll
    for (int L = 0; L < 2; ++L) load_lds16(gA[L],      Abase + 0 * A_SLOT + dOff[L]);
#pragma unroll
    for (int L = 0; L < 2; ++L) load_lds16(gB[L],      Bbase + 0 * B_SLOT + dOff[L]);
#pragma unroll
    for (int L = 0; L < 2; ++L) load_lds16(gA[L] + 64, Abase + 1 * A_SLOT + dOff[L]);
    asm volatile("s_waitcnt vmcnt(2)" ::: "memory");
    __builtin_amdgcn_s_barrier();

    int sA = 0;   // A slot of tile t   (t % 3)
    int sB = 0;   // B slot of tile t   (t & 1)

    for (int t = 0; t < KT; ++t) {
        char* Ab = Abase + sA * A_SLOT;
        char* Bb = Bbase + sB * B_SLOT;
        const int sA2 = (sA >= 1) ? sA - 1 : 2;       // (t+2) % 3
        char* An = Abase + sA2 * A_SLOT;
        char* Bn = Bbase + (sB ^ 1) * B_SLOT;
        const bool pfB = (t + 1 < KT);
        const bool pfA = (t + 2 < KT);

#pragma unroll
        for (int ks = 0; ks < 2; ++ks) {
            const int kb = k0 ^ (ks << 6);

            // -- 8 ds_read_b128: wave's 4 A-frags + 4 B-frags, each once
            bf16x8 af[4]; bf16x8 bfr[4];
#pragma unroll
            for (int m = 0; m < 4; ++m) {
                const int r = wr * 64 + m * 16 + frow;
                af[m] = *reinterpret_cast<const bf16x8*>(Ab + r * 128 + kb);
            }
#pragma unroll
            for (int n = 0; n < 4; ++n) {
                const int r = wc * 64 + n * 16 + frow;
                bfr[n] = *reinterpret_cast<const bf16x8*>(Bb + r * 128 + kb);
            }

            // -- staging once per tile (ks0): B(t+1) first, then A(t+2)
            if (ks == 0) {
                if (pfB) {
#pragma unroll
                    for (int L = 0; L < 2; ++L)
                        load_lds16(gB[L] + (size_t)(t + 1) * 64, Bn + dOff[L]);
                }
                if (pfA) {
#pragma unroll
                    for (int L = 0; L < 2; ++L)
                        load_lds16(gA[L] + (size_t)(t + 2) * 64, An + dOff[L]);
                }
            }

            // -- 16 MFMA; compiler inserts counted lgkm waits
            __builtin_amdgcn_s_setprio(1);
#pragma unroll
            for (int m = 0; m < 4; ++m)
#pragma unroll
                for (int n = 0; n < 4; ++n)
                    acc[m][n] = __builtin_amdgcn_mfma_f32_16x16x32_bf16(
                        af[m], bfr[n], acc[m][n], 0, 0, 0);
            __builtin_amdgcn_s_setprio(0);
        }

        // -- ONE barrier per K-tile, counted vmcnt (A(t+2) stays in flight)
        if (t < KT - 2)       asm volatile("s_waitcnt vmcnt(2)" ::: "memory");
        else if (t == KT - 2) asm volatile("s_waitcnt vmcnt(0)" ::: "memory");
        __builtin_amdgcn_s_barrier();

        sA = (sA < 2) ? sA + 1 : 0;
        sB ^= 1;
    }

    // ---- epilogue: C/D layout col=lane&15, row=(lane>>4)*4+reg (verified)
    const int crow = (lane >> 4) * 4;
    const int ccol = lane & 15;
#pragma unroll
    for (int fm = 0; fm < 4; ++fm)
#pragma unroll
        for (int fn = 0; fn < 4; ++fn)
#pragma unroll
            for (int r = 0; r < 4; ++r) {
                const int row = row0 + wr * 64 + fm * 16 + crow + r;
                const int col = col0 + wc * 64 + fn * 16 + ccol;
                C[(size_t)row * OUT_F + col] = acc[fm][fn][r];
            }
}

// ============================================================================
// Fallback GEMM (round-1, verified): used only if ws too small for Xb
// ============================================================================
#define BM 128
#define BN 128
#define BK 64

__global__ __launch_bounds__(256, 2) void gemm_x_wt_kernel(
    const float* __restrict__ X,
    const short* __restrict__ WT,
    float* __restrict__ C)
{
    __shared__ short As2[BM * BK];
    __shared__ short Bs2[BN * BK];

    const int bn = blockIdx.x;
    const int bm = blockIdx.y;
    const int tid  = threadIdx.x;
    const int lane = tid & 63;
    const int wid  = tid >> 6;
    const int wr   = wid >> 1;
    const int wc   = wid & 1;

    const int row0 = bm * BM;
    const int col0 = bn * BN;
    const int frow = lane & 15;
    const int fk   = (lane >> 4) * 8;

    f32x4 acc[4][4] = {};

    for (int kt = 0; kt < IN_F / BK; ++kt) {
        float4 a0[4], a1[4];
#pragma unroll
        for (int j = 0; j < 4; ++j) {
            const int flat = (j * 256 + tid) * 8;
            const int r = flat >> 6;
            const int c = flat & (BK - 1);
            const float* src = X + (size_t)(row0 + r) * IN_F + kt * BK + c;
            a0[j] = *reinterpret_cast<const float4*>(src);
            a1[j] = *reinterpret_cast<const float4*>(src + 4);
        }
        __syncthreads();
#pragma unroll
        for (int j = 0; j < 4; ++j) {
            const int flat = (j * 256 + tid) * 8;
            const int r = flat >> 6;
            const int c = flat & (BK - 1);
            load_lds16(WT + (size_t)(col0 + r) * IN_F + kt * BK + c, &Bs2[flat]);
        }
#pragma unroll
        for (int j = 0; j < 4; ++j) {
            const int flat = (j * 256 + tid) * 8;
            bf16x8 h;
            h[0] = f2bf(a0[j].x); h[1] = f2bf(a0[j].y);
            h[2] = f2bf(a0[j].z); h[3] = f2bf(a0[j].w);
            h[4] = f2bf(a1[j].x); h[5] = f2bf(a1[j].y);
            h[6] = f2bf(a1[j].z); h[7] = f2bf(a1[j].w);
            *reinterpret_cast<bf16x8*>(&As2[flat]) = h;
        }
        __syncthreads();
#pragma unroll
        for (int s = 0; s < 2; ++s) {
            bf16x8 af[4], bfr[4];
#pragma unroll
            for (int m = 0; m < 4; ++m) {
                const int row = wr * 64 + m * 16 + frow;
                af[m] = *reinterpret_cast<const bf16x8*>(&As2[row * BK + s * 32 + fk]);
            }
#pragma unroll
            for (int n = 0; n < 4; ++n) {
                const int col = wc * 64 + n * 16 + frow;
                bfr[n] = *reinterpret_cast<const bf16x8*>(&Bs2[col * BK + s * 32 + fk]);
            }
#pragma unroll
            for (int m = 0; m < 4; ++m)
#pragma unroll
                for (int n = 0; n < 4; ++n)
                    acc[m][n] = __builtin_amdgcn_mfma_f32_16x16x32_bf16(
                        af[m], bfr[n], acc[m][n], 0, 0, 0);
        }
    }

    const int crow = (lane >> 4) * 4;
    const int ccol = lane & 15;
#pragma unroll
    for (int m = 0; m < 4; ++m)
#pragma unroll
        for (int n = 0; n < 4; ++n)
#pragma unroll
            for (int r = 0; r < 4; ++r) {
                const int row = row0 + wr * 64 + m * 16 + crow + r;
                const int col = col0 + wc * 64 + n * 16 + ccol;
                C[(size_t)row * OUT_F + col] = acc[m][n][r];
            }
}

// ============================================================================
extern "C" void kernel_launch(void* const* d_in, const int* in_sizes, int n_in,
                              void* d_out, int out_size, void* d_ws, size_t ws_size,
                              hipStream_t stream) {
    const float* x       = (const float*)d_in[0];
    const int*   qweight = (const int*)  d_in[1];
    const int*   qzeros  = (const int*)  d_in[2];
    const float* scales  = (const float*)d_in[3];
    float*       out     = (float*)d_out;

    const size_t WT_BYTES = (size_t)OUT_F * IN_F * 2;   // 33.5 MB
    const size_t XB_BYTES = (size_t)M_ROWS * IN_F * 2;  // 67.1 MB

    short* wt = (short*)d_ws;

    if (ws_size >= WT_BYTES + XB_BYTES) {
        short* xb = (short*)((char*)d_ws + WT_BYTES);
        prepass_kernel<<<DQ_BLOCKS + XC_BLOCKS, 256, 0, stream>>>(
            qweight, qzeros, scales, x, wt, xb);
        dim3 grid(OUT_F / 256, M_ROWS / 256);   // (16, 32)
        gemm16_kernel<<<grid, 1024, 0, stream>>>(xb, wt, out);
    } else {
        prepass_kernel<<<DQ_BLOCKS, 256, 0, stream>>>(
            qweight, qzeros, scales, x, wt, (short*)nullptr);
        dim3 grid(OUT_F / BN, M_ROWS / BM);
        gemm_x_wt_kernel<<<grid, 256, 0, stream>>>(x, wt, out);
    }
}

// Round 13
// 266.443 us; speedup vs baseline: 1.4565x; 1.0086x over previous
//
#include <hip/hip_runtime.h>
#include <stdint.h>

// Problem constants
#define IN_F   4096
#define OUT_F  4096
#define M_ROWS 8192      // 4 * 2048
#define KT     (IN_F / 64)   // 64 K-tiles of BK=64

typedef __attribute__((ext_vector_type(8))) short  bf16x8;
typedef __attribute__((ext_vector_type(4))) float  f32x4;

__device__ __forceinline__ short f2bf(float f) {
    union { float f; uint32_t u; } v; v.f = f;
    uint32_t r = v.u + 0x7FFFu + ((v.u >> 16) & 1u);
    return (short)(r >> 16);
}

__device__ __forceinline__ void load_lds16(const void* gsrc, void* lds) {
    __builtin_amdgcn_global_load_lds(
        (const __attribute__((address_space(1))) uint32_t*)gsrc,
        (__attribute__((address_space(3))) uint32_t*)lds,
        16, 0, 0);
}

// ============================================================================
// Kernel 1: FUSED prepass (verified r9): dequant + X fp32->bf16
// ============================================================================
#define DQ_BLOCKS ((OUT_F * (IN_F / 8)) / 256)      // 8192
#define XC_BLOCKS ((M_ROWS * IN_F / 8) / 256)       // 16384

__global__ void prepass_kernel(const int* __restrict__ qweight,
                               const int* __restrict__ qzeros,
                               const float* __restrict__ scales,
                               const float* __restrict__ x,
                               short* __restrict__ wt,
                               short* __restrict__ xb)
{
    const int bid = blockIdx.x;
    if (bid < DQ_BLOCKS) {
        int t  = bid * 256 + threadIdx.x;
        int n  = t >> 9;
        int kw = t & 511;
        int g  = kw >> 4;

        float s = scales[g * OUT_F + n];
        uint32_t zw = (uint32_t)qzeros[g * (OUT_F / 8) + (n >> 3)];
        float z1 = (float)((zw >> (4 * (n & 7))) & 0xFu) + 1.0f;
        uint32_t q = (uint32_t)qweight[kw * OUT_F + n];

        bf16x8 out;
#pragma unroll
        for (int i = 0; i < 8; ++i) {
            float w = s * ((float)((q >> (4 * i)) & 0xFu) - z1);
            out[i] = f2bf(w);
        }
        *reinterpret_cast<bf16x8*>(&wt[(size_t)n * IN_F + kw * 8]) = out;
    } else {
        int t = (bid - DQ_BLOCKS) * 256 + threadIdx.x;
        const float4* src = reinterpret_cast<const float4*>(x) + (size_t)t * 2;
        float4 a = src[0], b = src[1];
        bf16x8 h;
        h[0] = f2bf(a.x); h[1] = f2bf(a.y); h[2] = f2bf(a.z); h[3] = f2bf(a.w);
        h[4] = f2bf(b.x); h[5] = f2bf(b.y); h[6] = f2bf(b.z); h[7] = f2bf(b.w);
        reinterpret_cast<bf16x8*>(xb)[t] = h;
    }
}

// ============================================================================
// Kernel 2: 256x256 GEMM — r12 structure (verified best: 222.5us, 58.7% Mfma,
// 4 waves/SIMD, 0 conflicts, port ~79 B/cy ~= b128 ceiling) + two tweaks:
//   (1) T1 XCD chunk swizzle: swz=(bid&7)*64+(bid>>3); XCD x covers grid rows
//       4x..4x+3 (all 16 cols) -> 4 contiguous A-panels per XCD = L2 hits.
//   (2) staging split: B(t+1) 2 gloads in ks0, A(t+2) 2 gloads in ks1 —
//       spreads LDS write-port pressure; ledger unchanged:
//       queue [A(t+1)2 | B(t+1)2 | A(t+2)2], end-of-tile vmcnt(2) drains
//       A(t+1)+B(t+1), keeps A(t+2). t==KT-2: vmcnt(0).
//   16 waves (1024 thr, 4Mx4N), 64x64/wave, acc 64 AGPR + 64 VGPR = 128 cap.
// ============================================================================
#define A_SLOT 32768
#define B_SLOT 32768

__global__ __launch_bounds__(1024, 1) void gemm16_kernel(
    const short* __restrict__ Xb,   // [M_ROWS][IN_F] bf16
    const short* __restrict__ WT,   // [OUT_F][IN_F] bf16
    float* __restrict__ C)          // [M_ROWS][OUT_F]
{
    __shared__ short AsBuf[3 * 256 * 64];   // 96 KB
    __shared__ short BsBuf[2 * 256 * 64];   // 64 KB
    char* const Abase = (char*)AsBuf;
    char* const Bbase = (char*)BsBuf;

    const int tid  = threadIdx.x;   // 0..1023
    const int lane = tid & 63;
    const int wid  = tid >> 6;      // 0..15
    const int wr   = wid >> 2;      // 0..3  (M quarter)
    const int wc   = wid & 3;       // 0..3  (N quarter)

    // ---- T1 XCD chunk swizzle (bijective: 512 % 8 == 0)
    const int bid  = blockIdx.x;               // 0..511
    const int swz  = (bid & 7) * 64 + (bid >> 3);
    const int row0 = (swz >> 4) * 256;          // 32 row-tiles
    const int col0 = (swz & 15) * 256;          // 16 col-tiles

    // ---- staging geometry (verified r12): thread covers slot bytes
    //      [L*16384 + tid*16); row = L*128 + (tid>>3); pre-swizzled source col
    const int rL0 = tid >> 3;                               // 0..127
    const int csw = ((tid & 7) << 3) ^ ((rL0 & 7) << 3);
    const short* gA[2]; const short* gB[2]; int dOff[2];
#pragma unroll
    for (int L = 0; L < 2; ++L) {
        const int r = L * 128 + rL0;
        gA[L] = Xb + (size_t)(row0 + r) * IN_F + csw;
        gB[L] = WT + (size_t)(col0 + r) * IN_F + csw;
        dOff[L] = L * 16384 + tid * 16;
    }

    // ---- read geometry (verified): frag(ks) at byte k0 ^ (ks<<6)
    const int frow = lane & 15;
    const int k0   = ((lane >> 4) << 4) ^ ((frow & 7) << 4);

    f32x4 acc[4][4] = {};   // 64 AGPR: wave's 64x64 output

    // ---- prologue: A(0)[2], B(0)[2], A(1)[2]; vmcnt(2) leaves A(1) flying
#pragma unroll
    for (int L = 0; L < 2; ++L) load_lds16(gA[L],      Abase + 0 * A_SLOT + dOff[L]);
#pragma unroll
    for (int L = 0; L < 2; ++L) load_lds16(gB[L],      Bbase + 0 * B_SLOT + dOff[L]);
#pragma unroll
    for (int L = 0; L < 2; ++L) load_lds16(gA[L] + 64, Abase + 1 * A_SLOT + dOff[L]);
    asm volatile("s_waitcnt vmcnt(2)" ::: "memory");
    __builtin_amdgcn_s_barrier();

    int sA = 0;   // A slot of tile t   (t % 3)
    int sB = 0;   // B slot of tile t   (t & 1)

    for (int t = 0; t < KT; ++t) {
        char* Ab = Abase + sA * A_SLOT;
        char* Bb = Bbase + sB * B_SLOT;
        const int sA2 = (sA >= 1) ? sA - 1 : 2;       // (t+2) % 3
        char* An = Abase + sA2 * A_SLOT;
        char* Bn = Bbase + (sB ^ 1) * B_SLOT;
        const bool pfB = (t + 1 < KT);
        const bool pfA = (t + 2 < KT);

#pragma unroll
        for (int ks = 0; ks < 2; ++ks) {
            const int kb = k0 ^ (ks << 6);

            // -- 8 ds_read_b128: wave's 4 A-frags + 4 B-frags, each once
            bf16x8 af[4]; bf16x8 bfr[4];
#pragma unroll
            for (int m = 0; m < 4; ++m) {
                const int r = wr * 64 + m * 16 + frow;
                af[m] = *reinterpret_cast<const bf16x8*>(Ab + r * 128 + kb);
            }
#pragma unroll
            for (int n = 0; n < 4; ++n) {
                const int r = wc * 64 + n * 16 + frow;
                bfr[n] = *reinterpret_cast<const bf16x8*>(Bb + r * 128 + kb);
            }

            // -- staging split: B(t+1) in ks0, A(t+2) in ks1 (queue order
            //    preserved for the counted ledger: B older than A)
            if (ks == 0) {
                if (pfB) {
#pragma unroll
                    for (int L = 0; L < 2; ++L)
                        load_lds16(gB[L] + (size_t)(t + 1) * 64, Bn + dOff[L]);
                }
            } else {
                if (pfA) {
#pragma unroll
                    for (int L = 0; L < 2; ++L)
                        load_lds16(gA[L] + (size_t)(t + 2) * 64, An + dOff[L]);
                }
            }

            // -- 16 MFMA; compiler inserts counted lgkm waits
            __builtin_amdgcn_s_setprio(1);
#pragma unroll
            for (int m = 0; m < 4; ++m)
#pragma unroll
                for (int n = 0; n < 4; ++n)
                    acc[m][n] = __builtin_amdgcn_mfma_f32_16x16x32_bf16(
                        af[m], bfr[n], acc[m][n], 0, 0, 0);
            __builtin_amdgcn_s_setprio(0);
        }

        // -- ONE barrier per K-tile, counted vmcnt (A(t+2) stays in flight)
        if (t < KT - 2)       asm volatile("s_waitcnt vmcnt(2)" ::: "memory");
        else if (t == KT - 2) asm volatile("s_waitcnt vmcnt(0)" ::: "memory");
        __builtin_amdgcn_s_barrier();

        sA = (sA < 2) ? sA + 1 : 0;
        sB ^= 1;
    }

    // ---- epilogue: C/D layout col=lane&15, row=(lane>>4)*4+reg (verified)
    const int crow = (lane >> 4) * 4;
    const int ccol = lane & 15;
#pragma unroll
    for (int fm = 0; fm < 4; ++fm)
#pragma unroll
        for (int fn = 0; fn < 4; ++fn)
#pragma unroll
            for (int r = 0; r < 4; ++r) {
                const int row = row0 + wr * 64 + fm * 16 + crow + r;
                const int col = col0 + wc * 64 + fn * 16 + ccol;
                C[(size_t)row * OUT_F + col] = acc[fm][fn][r];
            }
}

// ============================================================================
// Fallback GEMM (round-1, verified): used only if ws too small for Xb
// ============================================================================
#define BM 128
#define BN 128
#define BK 64

__global__ __launch_bounds__(256, 2) void gemm_x_wt_kernel(
    const float* __restrict__ X,
    const short* __restrict__ WT,
    float* __restrict__ C)
{
    __shared__ short As2[BM * BK];
    __shared__ short Bs2[BN * BK];

    const int bn = blockIdx.x;
    const int bm = blockIdx.y;
    const int tid  = threadIdx.x;
    const int lane = tid & 63;
    const int wid  = tid >> 6;
    const int wr   = wid >> 1;
    const int wc   = wid & 1;

    const int row0 = bm * BM;
    const int col0 = bn * BN;
    const int frow = lane & 15;
    const int fk   = (lane >> 4) * 8;

    f32x4 acc[4][4] = {};

    for (int kt = 0; kt < IN_F / BK; ++kt) {
        float4 a0[4], a1[4];
#pragma unroll
        for (int j = 0; j < 4; ++j) {
            const int flat = (j * 256 + tid) * 8;
            const int r = flat >> 6;
            const int c = flat & (BK - 1);
            const float* src = X + (size_t)(row0 + r) * IN_F + kt * BK + c;
            a0[j] = *reinterpret_cast<const float4*>(src);
            a1[j] = *reinterpret_cast<const float4*>(src + 4);
        }
        __syncthreads();
#pragma unroll
        for (int j = 0; j < 4; ++j) {
            const int flat = (j * 256 + tid) * 8;
            const int r = flat >> 6;
            const int c = flat & (BK - 1);
            load_lds16(WT + (size_t)(col0 + r) * IN_F + kt * BK + c, &Bs2[flat]);
        }
#pragma unroll
        for (int j = 0; j < 4; ++j) {
            const int flat = (j * 256 + tid) * 8;
            bf16x8 h;
            h[0] = f2bf(a0[j].x); h[1] = f2bf(a0[j].y);
            h[2] = f2bf(a0[j].z); h[3] = f2bf(a0[j].w);
            h[4] = f2bf(a1[j].x); h[5] = f2bf(a1[j].y);
            h[6] = f2bf(a1[j].z); h[7] = f2bf(a1[j].w);
            *reinterpret_cast<bf16x8*>(&As2[flat]) = h;
        }
        __syncthreads();
#pragma unroll
        for (int s = 0; s < 2; ++s) {
            bf16x8 af[4], bfr[4];
#pragma unroll
            for (int m = 0; m < 4; ++m) {
                const int row = wr * 64 + m * 16 + frow;
                af[m] = *reinterpret_cast<const bf16x8*>(&As2[row * BK + s * 32 + fk]);
            }
#pragma unroll
            for (int n = 0; n < 4; ++n) {
                const int col = wc * 64 + n * 16 + frow;
                bfr[n] = *reinterpret_cast<const bf16x8*>(&Bs2[col * BK + s * 32 + fk]);
            }
#pragma unroll
            for (int m = 0; m < 4; ++m)
#pragma unroll
                for (int n = 0; n < 4; ++n)
                    acc[m][n] = __builtin_amdgcn_mfma_f32_16x16x32_bf16(
                        af[m], bfr[n], acc[m][n], 0, 0, 0);
        }
    }

    const int crow = (lane >> 4) * 4;
    const int ccol = lane & 15;
#pragma unroll
    for (int m = 0; m < 4; ++m)
#pragma unroll
        for (int n = 0; n < 4; ++n)
#pragma unroll
            for (int r = 0; r < 4; ++r) {
                const int row = row0 + wr * 64 + m * 16 + crow + r;
                const int col = col0 + wc * 64 + n * 16 + ccol;
                C[(size_t)row * OUT_F + col] = acc[m][n][r];
            }
}

// ============================================================================
extern "C" void kernel_launch(void* const* d_in, const int* in_sizes, int n_in,
                              void* d_out, int out_size, void* d_ws, size_t ws_size,
                              hipStream_t stream) {
    const float* x       = (const float*)d_in[0];
    const int*   qweight = (const int*)  d_in[1];
    const int*   qzeros  = (const int*)  d_in[2];
    const float* scales  = (const float*)d_in[3];
    float*       out     = (float*)d_out;

    const size_t WT_BYTES = (size_t)OUT_F * IN_F * 2;   // 33.5 MB
    const size_t XB_BYTES = (size_t)M_ROWS * IN_F * 2;  // 67.1 MB

    short* wt = (short*)d_ws;

    if (ws_size >= WT_BYTES + XB_BYTES) {
        short* xb = (short*)((char*)d_ws + WT_BYTES);
        prepass_kernel<<<DQ_BLOCKS + XC_BLOCKS, 256, 0, stream>>>(
            qweight, qzeros, scales, x, wt, xb);
        gemm16_kernel<<<(M_ROWS / 256) * (OUT_F / 256), 1024, 0, stream>>>(xb, wt, out);
    } else {
        prepass_kernel<<<DQ_BLOCKS, 256, 0, stream>>>(
            qweight, qzeros, scales, x, wt, (short*)nullptr);
        dim3 grid(OUT_F / BN, M_ROWS / BM);
        gemm_x_wt_kernel<<<grid, 256, 0, stream>>>(x, wt, out);
    }
}